// Round 5
// baseline (2304.924 us; speedup 1.0000x reference)
//
#include <hip/hip_runtime.h>
#include <math.h>
#include <stdint.h>

#define NN 50000
#define NE 300000
#define NT4 200000  // NN*4 (dst,type) segments
#define NG 128
#define NSTEP 8
#define MPAD 50048  // 782*64
#define SCB 196     // ceil(NN/256)
#define SCB2 782    // ceil(NT4/256)
#define PCH 8
#define EM 64       // k_eagg M tile
#define ECAP 896    // LDS-staged edge capacity per tile (mean 384)

typedef __attribute__((ext_vector_type(8))) short bf16x8;
typedef __attribute__((ext_vector_type(8))) unsigned short u16x8;
typedef __attribute__((ext_vector_type(4))) float f32x4;
typedef unsigned short u16;
typedef unsigned int u32;

__device__ __forceinline__ float b2f(u16 u) {
  union { u32 i; float f; } c; c.i = ((u32)u) << 16; return c.f;
}
__device__ __forceinline__ u16 f2b(float f) {
  union { float f; u32 i; } c; c.f = f;
  u32 x = c.i;
  u32 r = (x + 0x7fffu + ((x >> 16) & 1u)) >> 16;
  return (u16)r;
}

__device__ __forceinline__ void load_lds16(const void* g, void* l) {
  __builtin_amdgcn_global_load_lds((const __attribute__((address_space(1))) u32*)g,
                                   (__attribute__((address_space(3))) u32*)l, 16, 0, 0);
}

// ---------------- weight prep ----------------
// Wt_e[t*256+col][k] = W_e[t][k][col]
__global__ void k_conv_we(const float* __restrict__ W_e, u16* __restrict__ Wt) {
  int i = blockIdx.x * 256 + threadIdx.x;  // 1024*256
  int c = i >> 8, d = i & 255;
  Wt[c * 256 + d] = f2b(W_e[(c >> 8) * 65536 + d * 256 + (c & 255)]);
}
// RZ weights: variant AH: k<256 -> W_ih[k][n], k>=256 -> W_hh[k-256][n]
//             variant HA: k<256 -> W_hh[k][n], k>=256 -> W_ih[k-256][n]
__global__ void k_conv_rz(const float* __restrict__ W_ih, const float* __restrict__ W_hh,
                          u16* __restrict__ ah, u16* __restrict__ ha) {
  int i = blockIdx.x * 256 + threadIdx.x;  // 512*512
  int n = i >> 9, k = i & 511;
  float va = (k < 256) ? W_ih[k * 768 + n] : W_hh[(k - 256) * 768 + n];
  float vh = (k < 256) ? W_hh[k * 768 + n] : W_ih[(k - 256) * 768 + n];
  ah[n * 512 + k] = f2b(va);
  ha[n * 512 + k] = f2b(vh);
}
// n-gate weights: Wt[n][k] = W[k][512+n]
__global__ void k_conv_n(const float* __restrict__ W, u16* __restrict__ Wt) {
  int i = blockIdx.x * 256 + threadIdx.x;  // 256*256
  int n = i >> 8, k = i & 255;
  Wt[n * 256 + k] = f2b(W[k * 768 + 512 + n]);
}
__global__ void k_brz(const float* __restrict__ b_ih, const float* __restrict__ b_hh,
                      float* __restrict__ b_rz) {
  int i = blockIdx.x * 256 + threadIdx.x;
  if (i < 512) b_rz[i] = b_ih[i] + b_hh[i];
}

// acat layout per row (768 cols): [hbA (256) | ab (256) | hbB (256)]
__global__ void k_init_h(const float* __restrict__ feat, u16* __restrict__ acat) {
  int i = blockIdx.x * 256 + threadIdx.x;  // MPAD*64
  int n = i >> 6, d = (i & 63) << 2;
  ushort4 o;
  if (n < NN) {
    float4 v = *(const float4*)(feat + (size_t)n * 1024 + d);
    o.x = f2b(v.x); o.y = f2b(v.y); o.z = f2b(v.z); o.w = f2b(v.w);
  } else {
    o.x = o.y = o.z = o.w = 0;
  }
  *(ushort4*)(acat + (size_t)n * 768 + d) = o;
}

// ---------------- CSR build over (dst*4+type) ----------------
__global__ void k_hist(const int* __restrict__ dst, const int* __restrict__ ety,
                       int* __restrict__ deg2) {
  int e = blockIdx.x * 256 + threadIdx.x;
  if (e < NE) atomicAdd(&deg2[dst[e] * 4 + ety[e]], 1);
}
__global__ void k_scan1(const int* __restrict__ deg2, int* __restrict__ part, int* __restrict__ bsum) {
  __shared__ int sh[256];
  int b = blockIdx.x, t = threadIdx.x;
  int i = b * 256 + t;
  int v = (i < NT4) ? deg2[i] : 0;
  sh[t] = v;
  __syncthreads();
  for (int off = 1; off < 256; off <<= 1) {
    int tmp = (t >= off) ? sh[t - off] : 0;
    __syncthreads();
    sh[t] += tmp;
    __syncthreads();
  }
  if (i < NT4) part[i] = sh[t] - v;
  if (t == 255) bsum[b] = sh[255];
}
__global__ void k_scan2(const int* __restrict__ bsum, int* __restrict__ boff) {
  __shared__ int sh[1024];
  int t = threadIdx.x;
  int v = (t < SCB2) ? bsum[t] : 0;
  sh[t] = v;
  __syncthreads();
  for (int off = 1; off < 1024; off <<= 1) {
    int tmp = (t >= off) ? sh[t - off] : 0;
    __syncthreads();
    sh[t] += tmp;
    __syncthreads();
  }
  boff[t] = sh[t] - v;
  if (t == 1023) boff[1024] = sh[1023];
}
__global__ void k_scan3(const int* __restrict__ part, const int* __restrict__ boff, int* __restrict__ rp2) {
  int i = blockIdx.x * 256 + threadIdx.x;
  if (i < NT4) rp2[i] = part[i] + boff[i >> 8];
  if (i == NT4) rp2[NT4] = boff[1024];
}
__global__ void k_scatter(const int* __restrict__ src, const int* __restrict__ dst,
                          const int* __restrict__ ety, const int* __restrict__ rp2,
                          int* __restrict__ cursor2, int* __restrict__ esrc) {
  int e = blockIdx.x * 256 + threadIdx.x;
  if (e < NE) {
    int seg = dst[e] * 4 + ety[e];
    int p = rp2[seg] + atomicAdd(&cursor2[seg], 1);
    esrc[p] = src[e];
  }
}
__global__ void k_cnt2(const int* __restrict__ deg2, ushort4* __restrict__ cnt2) {
  int v = blockIdx.x * 256 + threadIdx.x;
  if (v >= MPAD) return;
  ushort4 o;
  if (v < NN) {
    o.x = (u16)deg2[v * 4 + 0]; o.y = (u16)deg2[v * 4 + 1];
    o.z = (u16)deg2[v * 4 + 2]; o.w = (u16)deg2[v * 4 + 3];
  } else {
    o.x = o.y = o.z = o.w = 0;
  }
  cnt2[v] = o;
}
__global__ void k_gstart(const int* __restrict__ n2g, int* __restrict__ gstart) {
  int n = blockIdx.x * 256 + threadIdx.x;
  if (n >= NN) return;
  int g = n2g[n];
  int gp = (n == 0) ? -1 : n2g[n - 1];
  for (int x = gp + 1; x <= g; ++x) gstart[x] = n;
  if (n == NN - 1)
    for (int x = g + 1; x <= NG; ++x) gstart[x] = NN;
}

// ---------------- fused aggregate + e-GEMM (v3: direct-global B, few barriers) ----------------
// 512 threads, 8 waves (2M x 4N), M-tile 64. Per tile:
//   stage rp2 slice + contiguous esrc slice into LDS
//   for t in 0..3: gather-sum h[src] -> LDS S (4 rows round-robin per half-wave),
//                  MFMA S @ W_e[t] with B fragments read DIRECTLY from global (L2-hot)
//   epilogue: a = acc + sum_t cnt[v,t]*b_e[t] -> write ab
__global__ __launch_bounds__(512, 4) void k_eagg(
    const u16* __restrict__ acat, int hboff,
    const int* __restrict__ rp2, const int* __restrict__ esrc,
    const u16* __restrict__ Wt_e,
    const ushort4* __restrict__ cnt2, const float* __restrict__ b_e,
    u16* __restrict__ acat_out) {
  __shared__ __align__(16) char Ss[EM * 512];  // 32KB: [64 rows][256 k] bf16, XOR-swizzled
  __shared__ int Es[ECAP];
  __shared__ int Rp[257];
  const int tid = threadIdx.x;
  const int wv = tid >> 6, l = tid & 63;
  const int hw = tid >> 5, lw = tid & 31;
  const int m0 = blockIdx.x * EM;
  const int fr = l & 15, kq = l >> 4;
  const int wm = (wv >> 2) * 32, wn = (wv & 3) * 64;

  const int base4 = m0 * 4;
  const int e0 = rp2[base4];
  for (int i = tid; i <= 256; i += 512) {
    int idx = base4 + i;
    if (idx > NT4) idx = NT4;
    Rp[i] = rp2[idx] - e0;
  }
  {
    int idxe = base4 + 256;
    if (idxe > NT4) idxe = NT4;
    int ecnt = rp2[idxe] - e0;
    int ecl = ecnt < ECAP ? ecnt : ECAP;
    for (int i = tid; i < ecl; i += 512) Es[i] = esrc[e0 + i] * 768 + hboff;
  }
  __syncthreads();

  f32x4 acc[2][4];
#pragma unroll
  for (int m = 0; m < 2; ++m)
#pragma unroll
    for (int n = 0; n < 4; ++n) acc[m][n] = (f32x4){0.f, 0.f, 0.f, 0.f};

  for (int t = 0; t < 4; ++t) {
    if (t > 0) __syncthreads();  // prior MFMA reads of Ss done before overwrite
    // ---- gather: half-wave hw owns rows hw*4..hw*4+3, round-robin ----
    int cc[4], ee[4];
#pragma unroll
    for (int rr = 0; rr < 4; ++rr) {
      int li = (hw * 4 + rr) * 4 + t;
      cc[rr] = Rp[li];
      ee[rr] = Rp[li + 1];
    }
    float ar[4][8];
#pragma unroll
    for (int rr = 0; rr < 4; ++rr)
#pragma unroll
      for (int q = 0; q < 8; ++q) ar[rr][q] = 0.f;
    bool more = (cc[0] < ee[0]) | (cc[1] < ee[1]) | (cc[2] < ee[2]) | (cc[3] < ee[3]);
    while (more) {
      u16x8 v[4];
      bool p[4];
#pragma unroll
      for (int rr = 0; rr < 4; ++rr) {
        p[rr] = cc[rr] < ee[rr];
        if (p[rr]) {
          int rel = cc[rr];
          int off = (rel < ECAP) ? Es[rel] : (esrc[e0 + rel] * 768 + hboff);
          v[rr] = *(const u16x8*)(acat + (size_t)off + lw * 8);
        }
      }
#pragma unroll
      for (int rr = 0; rr < 4; ++rr) {
        if (p[rr]) {
#pragma unroll
          for (int q = 0; q < 8; ++q) ar[rr][q] += b2f(v[rr][q]);
          cc[rr]++;
        }
      }
      more = (cc[0] < ee[0]) | (cc[1] < ee[1]) | (cc[2] < ee[2]) | (cc[3] < ee[3]);
    }
#pragma unroll
    for (int rr = 0; rr < 4; ++rr) {
      int row = hw * 4 + rr;
      u16x8 o;
#pragma unroll
      for (int q = 0; q < 8; ++q) o[q] = f2b(ar[rr][q]);
      *(u16x8*)(Ss + row * 512 + ((lw * 16) ^ ((row & 7) << 4))) = o;
    }
    __syncthreads();  // S visible to all waves

    // ---- MFMA: acc += S @ W_e[t], B direct from global (L2-hot, no staging) ----
    const u16* Bw = Wt_e + (size_t)t * 65536;
#pragma unroll 2
    for (int k8 = 0; k8 < 8; ++k8) {
      bf16x8 af[2], bfr[4];
      int ka = (k8 * 32 + kq * 8) * 2;
#pragma unroll
      for (int m = 0; m < 2; ++m) {
        int R = wm + m * 16 + fr;
        af[m] = *(const bf16x8*)(Ss + R * 512 + (ka ^ ((R & 7) << 4)));
      }
#pragma unroll
      for (int n = 0; n < 4; ++n) {
        int R = wn + n * 16 + fr;
        bfr[n] = *(const bf16x8*)(Bw + (size_t)R * 256 + k8 * 32 + kq * 8);
      }
#pragma unroll
      for (int m = 0; m < 2; ++m)
#pragma unroll
        for (int n = 0; n < 4; ++n)
          acc[m][n] = __builtin_amdgcn_mfma_f32_16x16x32_bf16(af[m], bfr[n], acc[m][n], 0, 0, 0);
    }
  }

  // ---- epilogue: add per-node counted bias, write ab ----
  float bev[4][4];
#pragma unroll
  for (int n = 0; n < 4; ++n)
#pragma unroll
    for (int t = 0; t < 4; ++t) bev[n][t] = b_e[t * 256 + wn + n * 16 + fr];
#pragma unroll
  for (int m = 0; m < 2; ++m) {
#pragma unroll
    for (int j = 0; j < 4; ++j) {
      int rl = wm + m * 16 + kq * 4 + j;
      int v = m0 + rl;
      ushort4 c4 = cnt2[v];
      float c0 = c4.x, c1 = c4.y, c2 = c4.z, c3 = c4.w;
#pragma unroll
      for (int n = 0; n < 4; ++n) {
        int col = wn + n * 16 + fr;
        float val = acc[m][n][j] + c0 * bev[n][0] + c1 * bev[n][1] + c2 * bev[n][2] + c3 * bev[n][3];
        acat_out[(size_t)v * 768 + 256 + col] = f2b(val);
      }
    }
  }
}

// ---------------- fully fused GRU: r,z,in,hn GEMMs + combine, all in-register ----------------
// 512 threads, 8 waves (2M x 4N), M-tile 64, c-tile 256.
// acc_r[m][n] and acc_z[m][n] hold cols c and c+256 of the rz GEMM (paired B-rows),
// acc_i/acc_h the in/hn GEMMs at the same (row,c) -> combine needs no cross-thread traffic.
__global__ __launch_bounds__(512, 2) void k_gru2(
    const u16* __restrict__ acat, int rzoff, int hnewoff, int swap,
    const u16* __restrict__ Wrz, const u16* __restrict__ Wt_in, const u16* __restrict__ Wt_hn,
    const float* __restrict__ b_rz, const float* __restrict__ b_ih, const float* __restrict__ b_hh,
    u16* __restrict__ acat_out) {
  __shared__ __align__(16) char As1[64 * 512];  // 32KB: rz-A k 0..255
  __shared__ __align__(16) char As2[64 * 512];  // 32KB: rz-A k 256..511
  __shared__ __align__(16) char Bs[512 * 128];  // 64KB: B chunk [512 rows][64 k]
  const int tid = threadIdx.x;
  const int wv = tid >> 6, l = tid & 63;
  const int m0 = blockIdx.x * 64;
  const int fr = l & 15, kq = l >> 4;
  const int wm = (wv >> 2) * 32, wn = (wv & 3) * 64;

  // ---- stage As1/As2 once (inverse-swizzled source, linear dest) ----
#pragma unroll
  for (int p = 0; p < 4; ++p) {
    int row = p * 16 + wv * 2 + (l >> 5);
    int ksrc = ((l & 31) ^ (row & 7)) << 3;
    load_lds16(acat + (size_t)(m0 + row) * 768 + rzoff + ksrc, As1 + p * 8192 + wv * 1024);
    load_lds16(acat + (size_t)(m0 + row) * 768 + rzoff + 256 + ksrc, As2 + p * 8192 + wv * 1024);
  }

  f32x4 ar_[2][4], az_[2][4], ai_[2][4], ah_[2][4];
#pragma unroll
  for (int m = 0; m < 2; ++m)
#pragma unroll
    for (int n = 0; n < 4; ++n) {
      ar_[m][n] = (f32x4){0.f, 0.f, 0.f, 0.f};
      az_[m][n] = (f32x4){0.f, 0.f, 0.f, 0.f};
      ai_[m][n] = (f32x4){0.f, 0.f, 0.f, 0.f};
      ah_[m][n] = (f32x4){0.f, 0.f, 0.f, 0.f};
    }

  // ---- phase 1: r,z over K=512 ----
  for (int kc = 0; kc < 8; ++kc) {
#pragma unroll
    for (int p = 0; p < 8; ++p) {
      int brow = p * 64 + wv * 8 + (l >> 3);
      int ks = kc * 64 + (((l & 7) ^ (brow & 7)) << 3);
      load_lds16(Wrz + (size_t)brow * 512 + ks, Bs + p * 8192 + wv * 1024);
    }
    asm volatile("s_waitcnt vmcnt(0)" ::: "memory");
    __syncthreads();
    const char* Asrc = (kc < 4) ? As1 : As2;
    int kbase = (kc & 3) * 64;
#pragma unroll
    for (int kk = 0; kk < 64; kk += 32) {
      bf16x8 af[2], br4[4], bz4[4];
      int ka = (kbase + kk + kq * 8) * 2;
      int kb = (kk + kq * 8) * 2;
#pragma unroll
      for (int m = 0; m < 2; ++m) {
        int R = wm + m * 16 + fr;
        af[m] = *(const bf16x8*)(Asrc + R * 512 + (ka ^ ((R & 7) << 4)));
      }
#pragma unroll
      for (int n = 0; n < 4; ++n) {
        int Rr = wn + n * 16 + fr;
        int Rz = Rr + 256;
        br4[n] = *(const bf16x8*)(Bs + Rr * 128 + (kb ^ ((Rr & 7) << 4)));
        bz4[n] = *(const bf16x8*)(Bs + Rz * 128 + (kb ^ ((Rz & 7) << 4)));
      }
#pragma unroll
      for (int m = 0; m < 2; ++m)
#pragma unroll
        for (int n = 0; n < 4; ++n) {
          ar_[m][n] = __builtin_amdgcn_mfma_f32_16x16x32_bf16(af[m], br4[n], ar_[m][n], 0, 0, 0);
          az_[m][n] = __builtin_amdgcn_mfma_f32_16x16x32_bf16(af[m], bz4[n], az_[m][n], 0, 0, 0);
        }
    }
    __syncthreads();
  }

  // ---- phase 2: i_n (A=a) and h_n (A=h) over K=256; Bs rows 0..255=Wt_in, 256..511=Wt_hn ----
  const char* Asa = swap ? As1 : As2;
  const char* Ash = swap ? As2 : As1;
  for (int kc = 0; kc < 4; ++kc) {
#pragma unroll
    for (int p = 0; p < 8; ++p) {
      int brow = p * 64 + wv * 8 + (l >> 3);
      const u16* srcw = (brow < 256) ? (Wt_in + (size_t)brow * 256)
                                     : (Wt_hn + (size_t)(brow - 256) * 256);
      int ks = kc * 64 + (((l & 7) ^ (brow & 7)) << 3);
      load_lds16(srcw + ks, Bs + p * 8192 + wv * 1024);
    }
    asm volatile("s_waitcnt vmcnt(0)" ::: "memory");
    __syncthreads();
    int kbase = kc * 64;
#pragma unroll
    for (int kk = 0; kk < 64; kk += 32) {
      bf16x8 afa[2], afh[2], bi4[4], bh4[4];
      int ka = (kbase + kk + kq * 8) * 2;
      int kb = (kk + kq * 8) * 2;
#pragma unroll
      for (int m = 0; m < 2; ++m) {
        int R = wm + m * 16 + fr;
        afa[m] = *(const bf16x8*)(Asa + R * 512 + (ka ^ ((R & 7) << 4)));
        afh[m] = *(const bf16x8*)(Ash + R * 512 + (ka ^ ((R & 7) << 4)));
      }
#pragma unroll
      for (int n = 0; n < 4; ++n) {
        int Ri = wn + n * 16 + fr;
        int Rh = Ri + 256;
        bi4[n] = *(const bf16x8*)(Bs + Ri * 128 + (kb ^ ((Ri & 7) << 4)));
        bh4[n] = *(const bf16x8*)(Bs + Rh * 128 + (kb ^ ((Rh & 7) << 4)));
      }
#pragma unroll
      for (int m = 0; m < 2; ++m)
#pragma unroll
        for (int n = 0; n < 4; ++n) {
          ai_[m][n] = __builtin_amdgcn_mfma_f32_16x16x32_bf16(afa[m], bi4[n], ai_[m][n], 0, 0, 0);
          ah_[m][n] = __builtin_amdgcn_mfma_f32_16x16x32_bf16(afh[m], bh4[n], ah_[m][n], 0, 0, 0);
        }
    }
    __syncthreads();
  }

  // ---- epilogue: GRU combine fully in-register; h_old from Ash LDS ----
  float brb[4], bzb[4], bib[4], bhb[4];
#pragma unroll
  for (int n = 0; n < 4; ++n) {
    int c = wn + n * 16 + fr;
    brb[n] = b_rz[c];
    bzb[n] = b_rz[256 + c];
    bib[n] = b_ih[512 + c];
    bhb[n] = b_hh[512 + c];
  }
#pragma unroll
  for (int m = 0; m < 2; ++m) {
#pragma unroll
    for (int j = 0; j < 4; ++j) {
      int rl = wm + m * 16 + kq * 4 + j;
      int v = m0 + rl;
#pragma unroll
      for (int n = 0; n < 4; ++n) {
        int c = wn + n * 16 + fr;
        float r = 1.f / (1.f + expf(-(ar_[m][n][j] + brb[n])));
        float z = 1.f / (1.f + expf(-(az_[m][n][j] + bzb[n])));
        float in_ = ai_[m][n][j] + bib[n];
        float hn_ = ah_[m][n][j] + bhb[n];
        float ho = b2f(*(const u16*)(Ash + rl * 512 + ((c * 2) ^ ((rl & 7) << 4))));
        float ng = tanhf(in_ + r * hn_);
        acat_out[(size_t)v * 768 + hnewoff + c] = f2b((1.f - z) * ng + z * ho);
      }
    }
  }
}

// ---------------- pooling + head ----------------
__global__ __launch_bounds__(256) void k_pool(const u16* __restrict__ hb, const float* __restrict__ feat,
                                              const int* __restrict__ gstart, float* __restrict__ pooled) {
  int g = blockIdx.x, ch = blockIdx.y, t = threadIdx.x;
  int s = gstart[g], e = gstart[g + 1];
  int tot = e - s;
  int per = (tot + PCH - 1) / PCH;
  int ns = s + ch * per;
  int ne = ns + per < e ? ns + per : e;
  if (ns >= ne) return;
  int c = t << 2;
  float a0 = 0.f, a1 = 0.f, a2 = 0.f, a3 = 0.f;
  if (c < 256) {
    for (int n = ns; n < ne; ++n) {
      ushort4 u = *(const ushort4*)(hb + (size_t)n * 768 + c);
      a0 += b2f(u.x); a1 += b2f(u.y); a2 += b2f(u.z); a3 += b2f(u.w);
    }
  } else {
    for (int n = ns; n < ne; ++n) {
      float4 v = *(const float4*)(feat + (size_t)n * 1024 + c);
      a0 += v.x; a1 += v.y; a2 += v.z; a3 += v.w;
    }
  }
  atomicAdd(&pooled[g * 1024 + c], a0);
  atomicAdd(&pooled[g * 1024 + c + 1], a1);
  atomicAdd(&pooled[g * 1024 + c + 2], a2);
  atomicAdd(&pooled[g * 1024 + c + 3], a3);
}

__global__ __launch_bounds__(256) void k_head(const float* __restrict__ pooled,
                                              const int* __restrict__ gstart,
                                              const float* __restrict__ W1, const float* __restrict__ b1,
                                              const float* __restrict__ W2, const float* __restrict__ b2,
                                              float* __restrict__ out) {
  __shared__ float sp[1024];
  __shared__ float red[256];
  int g = blockIdx.x, t = threadIdx.x;
  float inv = 1.f / fmaxf((float)(gstart[g + 1] - gstart[g]), 1.f);
  for (int i = t; i < 1024; i += 256) sp[i] = pooled[g * 1024 + i] * inv;
  __syncthreads();
  float acc = b1[t];
  for (int k = 0; k < 1024; ++k) acc += sp[k] * W1[k * 256 + t];
  float hc = fmaxf(acc, 0.f);
  red[t] = hc * W2[t];
  __syncthreads();
  for (int s2 = 128; s2 > 0; s2 >>= 1) {
    if (t < s2) red[t] += red[t + s2];
    __syncthreads();
  }
  if (t == 0) out[g] = 1.f / (1.f + expf(-(red[0] + b2[0])));
}

extern "C" void kernel_launch(void* const* d_in, const int* in_sizes, int n_in, void* d_out, int out_size,
                              void* d_ws, size_t ws_size, hipStream_t stream) {
  const float* feat = (const float*)d_in[0];
  const float* W_e = (const float*)d_in[1];
  const float* b_e = (const float*)d_in[2];
  const float* W_ih = (const float*)d_in[3];
  const float* W_hh = (const float*)d_in[4];
  const float* b_ih = (const float*)d_in[5];
  const float* b_hh = (const float*)d_in[6];
  const float* W1 = (const float*)d_in[7];
  const float* b1 = (const float*)d_in[8];
  const float* W2 = (const float*)d_in[9];
  const float* b2 = (const float*)d_in[10];
  const int* src = (const int*)d_in[11];
  const int* dst = (const int*)d_in[12];
  const int* ety = (const int*)d_in[13];
  const int* n2g = (const int*)d_in[14];

  char* p = (char*)d_ws;
  auto alloc = [&](size_t b) { char* r = p; p += (b + 255) & ~(size_t)255; return r; };
  u16* acat = (u16*)alloc((size_t)MPAD * 768 * 2);  // [hbA | ab | hbB]
  u16* Wt_e = (u16*)alloc(1024 * 256 * 2);
  u16* Wt_rz_ah = (u16*)alloc(512 * 512 * 2);
  u16* Wt_rz_ha = (u16*)alloc(512 * 512 * 2);
  u16* Wt_in = (u16*)alloc(256 * 256 * 2);
  u16* Wt_hn = (u16*)alloc(256 * 256 * 2);
  float* b_rz = (float*)alloc(512 * 4);
  int* deg2 = (int*)alloc((size_t)NT4 * 4);
  int* part = (int*)alloc((size_t)NT4 * 4);
  int* bsum = (int*)alloc((size_t)SCB2 * 4);
  int* boff = (int*)alloc(1025 * 4);
  int* rp2 = (int*)alloc((size_t)(NT4 + 1) * 4);
  int* cursor2 = (int*)alloc((size_t)NT4 * 4);
  int* esrc = (int*)alloc((size_t)NE * 4);
  ushort4* cnt2 = (ushort4*)alloc((size_t)MPAD * 8);
  int* gstart = (int*)alloc((size_t)(NG + 1) * 4);
  float* pooled = (float*)alloc((size_t)NG * 1024 * 4);

  hipMemsetAsync(deg2, 0, (size_t)NT4 * 4, stream);
  hipMemsetAsync(cursor2, 0, (size_t)NT4 * 4, stream);
  hipMemsetAsync(pooled, 0, (size_t)NG * 1024 * 4, stream);

  k_conv_we<<<1024, 256, 0, stream>>>(W_e, Wt_e);
  k_conv_rz<<<1024, 256, 0, stream>>>(W_ih, W_hh, Wt_rz_ah, Wt_rz_ha);
  k_conv_n<<<256, 256, 0, stream>>>(W_ih, Wt_in);
  k_conv_n<<<256, 256, 0, stream>>>(W_hh, Wt_hn);
  k_brz<<<2, 256, 0, stream>>>(b_ih, b_hh, b_rz);
  k_init_h<<<MPAD / 4, 256, 0, stream>>>(feat, acat);
  k_hist<<<(NE + 255) / 256, 256, 0, stream>>>(dst, ety, deg2);
  k_scan1<<<SCB2, 256, 0, stream>>>(deg2, part, bsum);
  k_scan2<<<1, 1024, 0, stream>>>(bsum, boff);
  k_scan3<<<SCB2 + 1, 256, 0, stream>>>(part, boff, rp2);
  k_scatter<<<(NE + 255) / 256, 256, 0, stream>>>(src, dst, ety, rp2, cursor2, esrc);
  k_cnt2<<<(MPAD + 255) / 256, 256, 0, stream>>>(deg2, cnt2);
  k_gstart<<<SCB, 256, 0, stream>>>(n2g, gstart);

  for (int s = 0; s < NSTEP; ++s) {
    int hboff = (s & 1) ? 512 : 0;
    int hnewoff = 512 - hboff;
    int rzoff = (s & 1) ? 256 : 0;
    int swap = s & 1;  // As1 = a when odd, As2 = a when even
    const u16* Wrz = (s & 1) ? Wt_rz_ah : Wt_rz_ha;
    // fused gather + e-GEMM -> ab
    k_eagg<<<MPAD / EM, 512, 0, stream>>>(acat, hboff, rp2, esrc, Wt_e, cnt2, b_e, acat);
    // fused r,z,i_n,h_n GEMMs + GRU combine -> hnew
    k_gru2<<<MPAD / 64, 512, 0, stream>>>(acat, rzoff, hnewoff, swap, Wrz, Wt_in, Wt_hn,
                                          b_rz, b_ih, b_hh, acat);
  }

  // after step 7 (odd), final h is in hbA (offset 0)
  k_pool<<<dim3(NG, PCH), 256, 0, stream>>>(acat, feat, gstart, pooled);
  k_head<<<NG, 256, 0, stream>>>(pooled, gstart, W1, b1, W2, b2, (float*)d_out);
}